// Round 6
// baseline (277.595 us; speedup 1.0000x reference)
//
#include <hip/hip_runtime.h>
#include <hip/hip_bf16.h>

typedef __attribute__((ext_vector_type(8))) __bf16 bf16x8;
typedef __attribute__((ext_vector_type(4))) float f32x4;
typedef __attribute__((ext_vector_type(8))) float f32x8;

static __device__ __forceinline__ unsigned short bf16r(float f) {
  unsigned u = __builtin_bit_cast(unsigned, f);
  return (unsigned short)((u + 0x7FFFu + ((u >> 16) & 1u)) >> 16);
}

// tanh(x) = 1 - 2/(exp2(x*2*log2e)+1); saturates correctly for |x| large.
static __device__ __forceinline__ float ftanh(float x) {
  float e = __builtin_amdgcn_exp2f(x * 2.8853900817779268f);
  return 1.0f - 2.0f * __builtin_amdgcn_rcpf(e + 1.0f);
}

// ---------------- prologue: pack weights (bf16, frag order) + params --------
// ws layout (bytes):
//   w1pk: [0, 131072)          8 mtiles x 16 ksteps x 64 lanes x 8 bf16 (IDENTITY k)
//   w2pk: [131072, 163840)     8 mtiles x 4 ksteps x 64 lanes x 8 bf16 (pi-permuted k)
//   w3pk: [163840, 196608)     same as w2pk
//   ppk : [196608, 200192)     7 params x [q=4][32] f32
// w1 identity k-order: reg-loaded obs gives lane (q,rl) floats [q*8, q*8+8)
// of each 32-float kstep -> k-slot (q,j) <-> col s*32 + q*8 + j.
__global__ void pack_kernel(const float* __restrict__ w1, const float* __restrict__ w2,
                            const float* __restrict__ w3, const float* __restrict__ b1,
                            const float* __restrict__ g1, const float* __restrict__ be1,
                            const float* __restrict__ b2, const float* __restrict__ g2,
                            const float* __restrict__ be2, const float* __restrict__ b3,
                            unsigned short* __restrict__ w1pk, unsigned short* __restrict__ w2pk,
                            unsigned short* __restrict__ w3pk, float* __restrict__ ppk) {
  int idx = blockIdx.x * 256 + threadIdx.x;
  if (idx < 65536) {            // w1, identity k-order
    int j = idx & 7, l = (idx >> 3) & 63, s = (idx >> 9) & 15, t = idx >> 13;
    int row = t * 16 + (l & 15);
    int col = s * 32 + (l >> 4) * 8 + j;
    w1pk[idx] = bf16r(w1[row * 512 + col]);
  } else if (idx < 81920) {     // w2, pi-permuted k-order
    int i = idx - 65536;
    int j = i & 7, l = (i >> 3) & 63, s = (i >> 9) & 3, t = i >> 11;
    int row = t * 16 + (l & 15);
    int col = (2 * s + (j >> 2)) * 16 + (l >> 4) * 4 + (j & 3);
    w2pk[i] = bf16r(w2[row * 128 + col]);
  } else if (idx < 98304) {     // w3, pi-permuted k-order
    int i = idx - 81920;
    int j = i & 7, l = (i >> 3) & 63, s = (i >> 9) & 3, t = i >> 11;
    int row = t * 16 + (l & 15);
    int col = (2 * s + (j >> 2)) * 16 + (l >> 4) * 4 + (j & 3);
    w3pk[i] = bf16r(w3[row * 128 + col]);
  } else if (idx < 99200) {     // params: b1,g1,be1,b2,g2,be2,b3
    int i = idx - 98304;        // 0..895
    int p = i >> 7;
    int r = i & 127;
    int qq = r >> 5, ii = r & 31;
    int m = (ii >> 2) * 16 + qq * 4 + (ii & 3);
    const float* src = (p == 0) ? b1 : (p == 1) ? g1 : (p == 2) ? be1
                     : (p == 3) ? b2 : (p == 4) ? g2 : (p == 5) ? be2 : b3;
    ppk[i] = src[m];
  }
}

// ---------------- fused backbone: LDS-free, 4096 short blocks ---------------
// R17. Theory scoreboard: read-pattern family DEAD (R12 null, R13 -10%,
// R14/R16 -5%). Survivor: per-CU serial tail + chip-wide phase lockstep.
// 1 block/CU (forced by the 128KB w1 LDS tile) means block N's read-silent
// tail (epilogues + 1MB GEMM2/3 L2 frag reads ~7.6us + store drain + next
// block's w1 fill/barrier) can never overlap block N+1's HBM reads; all CUs
// entered round 1 together -> chip oscillates read-burst/read-silent.
// 4 x ~47us = 188us.
// Fix: DELETE the LDS tile. w1 frags read from global exactly like w2/w3
// frags already are (same 128KB stream for all waves on a CU -> L1 serves
// phase-neighbors; L2 backstop). No barrier, no fill. 4096 blocks x 256thr
// (4 waves, 64 rows), ~12us each, 16 rounds -> multiple blocks/CU
// co-resident at <=128 VGPR and jitter de-phases rounds -> chip-level read
// continuity. Predicted 140-165us; ~190 = phases already mixed / L1 offset;
// >=250 = w1-frag L2 wall -> amortize via 32-rows/wave next.
__global__ __launch_bounds__(256, 4)
void backbone_main(const float* __restrict__ obs,
                   const bf16x8* __restrict__ w1pk,
                   const bf16x8* __restrict__ w2pk,
                   const bf16x8* __restrict__ w3pk,
                   const float* __restrict__ ppk,
                   float* __restrict__ out) {
  const int tid  = threadIdx.x;
  const int lane = tid & 63;
  const int wv   = tid >> 6;          // 0..3
  const int q    = lane >> 4;
  const int rl   = lane & 15;
  // block owns 64 consecutive rows; wave owns 16 of them.
  const size_t brow = (size_t)blockIdx.x * 64 + (unsigned)(wv * 16) + (unsigned)rl;

  // lane q owns floats [q*8, q*8+8) of each 32-float kstep (identity map).
  const float* p0 = obs + brow * 512 + q * 8;

  f32x4 st[2][4];
#define LOAD_BATCH(buf, s0)                                                      \
  do {                                                                           \
    st[buf][0] = __builtin_nontemporal_load((const f32x4*)(p0 + (s0) * 32));     \
    st[buf][1] = __builtin_nontemporal_load((const f32x4*)(p0 + (s0) * 32 + 4)); \
    st[buf][2] = __builtin_nontemporal_load((const f32x4*)(p0 + (s0) * 32 + 32));\
    st[buf][3] = __builtin_nontemporal_load((const f32x4*)(p0 + (s0) * 32 + 36));\
  } while (0)

  // preload batches 0,1
  LOAD_BATCH(0, 0);
  LOAD_BATCH(1, 2);

  f32x4 acc[8];
#pragma unroll
  for (int t = 0; t < 8; ++t) acc[t] = (f32x4){0.f, 0.f, 0.f, 0.f};

  // ---- GEMM1: K=512, 8 batches x 2 ksteps, 2 batches in flight ----
  // w1 frags from global (L1/L2-cached; same stream for all waves on the CU).
#pragma unroll
  for (int bb = 0; bb < 8; ++bb) {
    const int cur = bb & 1;
    f32x4 a0 = st[cur][0], a1 = st[cur][1];
    f32x4 a2 = st[cur][2], a3 = st[cur][3];
    if (bb < 6) {
      LOAD_BATCH(cur, 2 * bb + 4);
    }
    f32x8 r0 = {a0.x, a0.y, a0.z, a0.w, a1.x, a1.y, a1.z, a1.w};
    f32x8 r1 = {a2.x, a2.y, a2.z, a2.w, a3.x, a3.y, a3.z, a3.w};
    bf16x8 b0 = __builtin_convertvector(r0, bf16x8);
    bf16x8 b1 = __builtin_convertvector(r1, bf16x8);
#pragma unroll
    for (int t = 0; t < 8; ++t) {
      bf16x8 af0 = w1pk[(t * 16 + 2 * bb) * 64 + lane];
      acc[t] = __builtin_amdgcn_mfma_f32_16x16x32_bf16(af0, b0, acc[t], 0, 0, 0);
    }
#pragma unroll
    for (int t = 0; t < 8; ++t) {
      bf16x8 af1 = w1pk[(t * 16 + 2 * bb + 1) * 64 + lane];
      acc[t] = __builtin_amdgcn_mfma_f32_16x16x32_bf16(af1, b1, acc[t], 0, 0, 0);
    }
  }
#undef LOAD_BATCH

  bf16x8 pkv[4];

  // ---- epilogue 1: +b1, LayerNorm(g1,be1), tanh, pack bf16 ----
  {
    const float* pb = ppk + 0 * 128 + q * 32;
    const float* pg = ppk + 1 * 128 + q * 32;
    const float* pe = ppk + 2 * 128 + q * 32;
    float s1 = 0.f, s2 = 0.f;
#pragma unroll
    for (int t = 0; t < 8; ++t) {
      f32x4 bb = *(const f32x4*)(pb + t * 4);
      f32x4 v = acc[t];
      v.x += bb.x; v.y += bb.y; v.z += bb.z; v.w += bb.w;
      acc[t] = v;
      s1 += (v.x + v.y) + (v.z + v.w);
      s2 += (v.x * v.x + v.y * v.y) + (v.z * v.z + v.w * v.w);
    }
    s1 += __shfl_xor(s1, 16, 64);
    s1 += __shfl_xor(s1, 32, 64);
    s2 += __shfl_xor(s2, 16, 64);
    s2 += __shfl_xor(s2, 32, 64);
    float mu  = s1 * (1.0f / 128.0f);
    float var = s2 * (1.0f / 128.0f) - mu * mu;
    float rs  = __builtin_amdgcn_rsqf(var + 1e-5f);
#pragma unroll
    for (int t2 = 0; t2 < 4; ++t2) {
      f32x4 ga = *(const f32x4*)(pg + (2 * t2) * 4);
      f32x4 gb = *(const f32x4*)(pg + (2 * t2 + 1) * 4);
      f32x4 ea = *(const f32x4*)(pe + (2 * t2) * 4);
      f32x4 eb = *(const f32x4*)(pe + (2 * t2 + 1) * 4);
      f32x4 va = acc[2 * t2];
      f32x4 vb = acc[2 * t2 + 1];
      f32x8 cat = {ftanh((va.x - mu) * rs * ga.x + ea.x),
                   ftanh((va.y - mu) * rs * ga.y + ea.y),
                   ftanh((va.z - mu) * rs * ga.z + ea.z),
                   ftanh((va.w - mu) * rs * ga.w + ea.w),
                   ftanh((vb.x - mu) * rs * gb.x + eb.x),
                   ftanh((vb.y - mu) * rs * gb.y + eb.y),
                   ftanh((vb.z - mu) * rs * gb.z + eb.z),
                   ftanh((vb.w - mu) * rs * gb.w + eb.w)};
      pkv[t2] = __builtin_convertvector(cat, bf16x8);
    }
  }

  // ---- GEMM2: K=128 (4 ksteps), B-frags are the lane's own pkv regs ----
#pragma unroll
  for (int t = 0; t < 8; ++t) acc[t] = (f32x4){0.f, 0.f, 0.f, 0.f};
#pragma unroll
  for (int s = 0; s < 4; ++s) {
#pragma unroll
    for (int t = 0; t < 8; ++t) {
      bf16x8 af = w2pk[(t * 4 + s) * 64 + lane];
      acc[t] = __builtin_amdgcn_mfma_f32_16x16x32_bf16(af, pkv[s], acc[t], 0, 0, 0);
    }
  }

  // ---- epilogue 2: +b2, LayerNorm(g2,be2), tanh, pack ----
  {
    const float* pb = ppk + 3 * 128 + q * 32;
    const float* pg = ppk + 4 * 128 + q * 32;
    const float* pe = ppk + 5 * 128 + q * 32;
    float s1 = 0.f, s2 = 0.f;
#pragma unroll
    for (int t = 0; t < 8; ++t) {
      f32x4 bb = *(const f32x4*)(pb + t * 4);
      f32x4 v = acc[t];
      v.x += bb.x; v.y += bb.y; v.z += bb.z; v.w += bb.w;
      acc[t] = v;
      s1 += (v.x + v.y) + (v.z + v.w);
      s2 += (v.x * v.x + v.y * v.y) + (v.z * v.z + v.w * v.w);
    }
    s1 += __shfl_xor(s1, 16, 64);
    s1 += __shfl_xor(s1, 32, 64);
    s2 += __shfl_xor(s2, 16, 64);
    s2 += __shfl_xor(s2, 32, 64);
    float mu  = s1 * (1.0f / 128.0f);
    float var = s2 * (1.0f / 128.0f) - mu * mu;
    float rs  = __builtin_amdgcn_rsqf(var + 1e-5f);
#pragma unroll
    for (int t2 = 0; t2 < 4; ++t2) {
      f32x4 ga = *(const f32x4*)(pg + (2 * t2) * 4);
      f32x4 gb = *(const f32x4*)(pg + (2 * t2 + 1) * 4);
      f32x4 ea = *(const f32x4*)(pe + (2 * t2) * 4);
      f32x4 eb = *(const f32x4*)(pe + (2 * t2 + 1) * 4);
      f32x4 va = acc[2 * t2];
      f32x4 vb = acc[2 * t2 + 1];
      f32x8 cat = {ftanh((va.x - mu) * rs * ga.x + ea.x),
                   ftanh((va.y - mu) * rs * ga.y + ea.y),
                   ftanh((va.z - mu) * rs * ga.z + ea.z),
                   ftanh((va.w - mu) * rs * ga.w + ea.w),
                   ftanh((vb.x - mu) * rs * gb.x + eb.x),
                   ftanh((vb.y - mu) * rs * gb.y + eb.y),
                   ftanh((vb.z - mu) * rs * gb.z + eb.z),
                   ftanh((vb.w - mu) * rs * gb.w + eb.w)};
      pkv[t2] = __builtin_convertvector(cat, bf16x8);
    }
  }

  // ---- GEMM3 ----
#pragma unroll
  for (int t = 0; t < 8; ++t) acc[t] = (f32x4){0.f, 0.f, 0.f, 0.f};
#pragma unroll
  for (int s = 0; s < 4; ++s) {
#pragma unroll
    for (int t = 0; t < 8; ++t) {
      bf16x8 af = w3pk[(t * 4 + s) * 64 + lane];
      acc[t] = __builtin_amdgcn_mfma_f32_16x16x32_bf16(af, pkv[s], acc[t], 0, 0, 0);
    }
  }

  // ---- final: +b3, tanh, store fp32 (dwordx4, nontemporal) ----
  {
    const float* pb = ppk + 6 * 128 + q * 32;
    float* orow = out + brow * 128 + q * 4;
#pragma unroll
    for (int t = 0; t < 8; ++t) {
      f32x4 bb = *(const f32x4*)(pb + t * 4);
      f32x4 v = acc[t];
      f32x4 o = {ftanh(v.x + bb.x), ftanh(v.y + bb.y),
                 ftanh(v.z + bb.z), ftanh(v.w + bb.w)};
      __builtin_nontemporal_store(o, (f32x4*)(orow + t * 16));
    }
  }
}

extern "C" void kernel_launch(void* const* d_in, const int* in_sizes, int n_in,
                              void* d_out, int out_size, void* d_ws, size_t ws_size,
                              hipStream_t stream) {
  const float* obs = (const float*)d_in[0];
  const float* w1  = (const float*)d_in[1];
  const float* b1  = (const float*)d_in[2];
  const float* g1  = (const float*)d_in[3];
  const float* be1 = (const float*)d_in[4];
  const float* w2  = (const float*)d_in[5];
  const float* b2  = (const float*)d_in[6];
  const float* g2  = (const float*)d_in[7];
  const float* be2 = (const float*)d_in[8];
  const float* w3  = (const float*)d_in[9];
  const float* b3  = (const float*)d_in[10];

  unsigned short* w1pk = (unsigned short*)d_ws;
  unsigned short* w2pk = w1pk + 65536;
  unsigned short* w3pk = w2pk + 16384;
  float*          ppk  = (float*)(w3pk + 16384);

  pack_kernel<<<388, 256, 0, stream>>>(w1, w2, w3, b1, g1, be1, b2, g2, be2, b3,
                                       w1pk, w2pk, w3pk, ppk);

  // LDS-free: 4096 blocks x 256 thr; each block = 64 rows
  backbone_main<<<4096, 256, 0, stream>>>(obs, (const bf16x8*)w1pk,
                                          (const bf16x8*)w2pk, (const bf16x8*)w3pk,
                                          ppk, (float*)d_out);
}